// Round 13
// baseline (483.321 us; speedup 1.0000x reference)
//
#include <hip/hip_runtime.h>
#include <math.h>
#include <stdint.h>

#pragma clang fp contract(off)  // belt (ignored by hipcc, kept for documentation)

#define T_DIM 32768
#define BLOCK 256

typedef float v4f __attribute__((ext_vector_type(4)));

// Suspenders (PROVEN round 12): make a float opaque to the backend so mul+add
// around it can NEVER be fused into v_fmac regardless of -ffp-contract=fast.
// Zero instructions; pins the blur to separate rte mul/add in source order,
// bitwise-matching the numpy reference (absmax 0.0039 vs 0.605 when fused).
#define FP_BARRIER(x) asm("" : "+v"(x))

// ---------- helpers ----------

__device__ __forceinline__ uint32_t float_key(float f) {
    // monotonic mapping float -> uint32; key > 0x80000000u  <=>  f > 0
    uint32_t u = __float_as_uint(f);
    return (u & 0x80000000u) ? ~u : (u | 0x80000000u);
}

__device__ __forceinline__ int reflect_idx(int t) {
    if (t < 0) t = -t;
    if (t >= T_DIM) t = 2 * T_DIM - 2 - t;
    return t;
}

__device__ __forceinline__ float blur7(const float* __restrict__ w,
                                       const float* taps) {
    float acc = w[0] * taps[0];
    FP_BARRIER(acc);
    #pragma unroll
    for (int d = 1; d < 7; ++d) {
        float p = w[d] * taps[d];
        FP_BARRIER(p);
        acc = acc + p;
        FP_BARRIER(acc);
    }
    return acc;
}

// ---------- kernels ----------

__global__ void init_ws_kernel(uint32_t* ws) { ws[0] = 0u; }

// Single data pass: computes blurred+NMS+vel outputs (assuming prev_max>0,
// the overwhelmingly-common case) AND the global onset max (block-reduced,
// one atomicMax per block). fixup_kernel corrects the rare prev_max<=0 case.
__global__ __launch_bounds__(BLOCK) void fused_kernel(
    const float* __restrict__ onset, const float* __restrict__ vel,
    const float* __restrict__ pth, uint32_t* __restrict__ ws,
    float* __restrict__ probs_out, float* __restrict__ vels_out,
    float w0, float w1, float w2, float w3, float w4, float w5, float w6) {

    const int row = blockIdx.y;
    const int j0 = (blockIdx.x * BLOCK + threadIdx.x) * 4;  // 4 outputs per thread
    const size_t base = (size_t)row * T_DIM;

    const float pthresh = pth[0];
    const float w[7] = {w0, w1, w2, w3, w4, w5, w6};

    float pb[6], vv[6];
    float lmax = -INFINITY;  // max over this thread's 4 owned onset values

    if (j0 >= 4 && j0 + 8 <= T_DIM) {
        const v4f* x4 = reinterpret_cast<const v4f*>(onset + base + j0 - 4);
        v4f A = x4[0], Bv = x4[1], C = x4[2];
        float xx[12] = {A.x, A.y, A.z, A.w, Bv.x, Bv.y, Bv.z, Bv.w, C.x, C.y, C.z, C.w};

        const v4f* v4 = reinterpret_cast<const v4f*>(vel + base + j0 - 4);
        v4f Vm = v4[0], Vc = v4[1], Vp = v4[2];
        vv[0] = Vm.w; vv[1] = Vc.x; vv[2] = Vc.y; vv[3] = Vc.z; vv[4] = Vc.w; vv[5] = Vp.x;

        lmax = fmaxf(fmaxf(xx[4], xx[5]), fmaxf(xx[6], xx[7]));  // onset[j0..j0+3]

        #pragma unroll
        for (int q = 0; q < 6; ++q)
            pb[q] = blur7(w, &xx[q]);  // t = j0+q-1, taps xx[q..q+6]
    } else {
        const float* x = onset + base;
        const float* v = vel + base;
        #pragma unroll
        for (int j = 0; j < 4; ++j)
            lmax = fmaxf(lmax, x[j0 + j]);  // owned t always in range
        #pragma unroll
        for (int q = 0; q < 6; ++q) {
            int t = j0 + q - 1;
            vv[q] = v[reflect_idx(t)];
            if (t < 0 || t >= T_DIM) {
                pb[q] = -INFINITY;  // NMS constant pad
            } else {
                float taps[7];
                #pragma unroll
                for (int d = 0; d < 7; ++d)
                    taps[d] = x[reflect_idx(t - 3 + d)];
                pb[q] = blur7(w, taps);
            }
        }
    }

    float po[4], vo[4];
    #pragma unroll
    for (int j = 0; j < 4; ++j) {
        float p = pb[j + 1];
        float pooled = fmaxf(fmaxf(pb[j], pb[j + 1]), pb[j + 2]);
        float o = (p == pooled) ? p : 0.0f;
        o = (o >= pthresh) ? o : 0.0f;
        po[j] = o;
        float a = (vv[j] + vv[j + 1]) + vv[j + 2];  // adds+div: no contraction hazard
        float vmean = a / 3.0f;
        vo[j] = (o > 0.0f) ? vmean : 0.0f;
    }

    v4f pov = {po[0], po[1], po[2], po[3]};
    v4f vov = {vo[0], vo[1], vo[2], vo[3]};
    __builtin_nontemporal_store(pov, reinterpret_cast<v4f*>(&probs_out[base + j0]));
    __builtin_nontemporal_store(vov, reinterpret_cast<v4f*>(&vels_out[base + j0]));

    // ---- global-max contribution: wave butterfly -> LDS -> 1 atomic/block ----
    #pragma unroll
    for (int off = 32; off > 0; off >>= 1)
        lmax = fmaxf(lmax, __shfl_xor(lmax, off));
    __shared__ float red[BLOCK / 64];
    if ((threadIdx.x & 63) == 0) red[threadIdx.x >> 6] = lmax;
    __syncthreads();
    if (threadIdx.x == 0) {
        #pragma unroll
        for (int i = 1; i < BLOCK / 64; ++i) lmax = fmaxf(lmax, red[i]);
        atomicMax(ws, float_key(lmax));
    }
}

// Guard: if prev_max > 0 (the test-data case), fused_kernel's output is
// already correct -> every block exits after one uniform scalar read.
// Otherwise rewrite outputs using RAW onset (reference's where-branch).
__global__ __launch_bounds__(BLOCK) void fixup_kernel(
    const float* __restrict__ onset, const float* __restrict__ vel,
    const float* __restrict__ pth, const uint32_t* __restrict__ ws,
    float* __restrict__ probs_out, float* __restrict__ vels_out) {

    if (ws[0] > 0x80000000u) return;  // prev_max > 0

    const int row = blockIdx.y;
    const int j0 = (blockIdx.x * BLOCK + threadIdx.x) * 4;
    const size_t base = (size_t)row * T_DIM;
    const float pthresh = pth[0];
    const float* x = onset + base;
    const float* v = vel + base;

    float pb[6], vv[6];
    #pragma unroll
    for (int q = 0; q < 6; ++q) {
        int t = j0 + q - 1;
        vv[q] = v[reflect_idx(t)];
        pb[q] = (t < 0 || t >= T_DIM) ? -INFINITY : x[t];  // raw onset, -inf pad
    }

    float po[4], vo[4];
    #pragma unroll
    for (int j = 0; j < 4; ++j) {
        float p = pb[j + 1];
        float pooled = fmaxf(fmaxf(pb[j], pb[j + 1]), pb[j + 2]);
        float o = (p == pooled) ? p : 0.0f;
        o = (o >= pthresh) ? o : 0.0f;
        po[j] = o;
        float a = (vv[j] + vv[j + 1]) + vv[j + 2];
        float vmean = a / 3.0f;
        vo[j] = (o > 0.0f) ? vmean : 0.0f;
    }

    v4f pov = {po[0], po[1], po[2], po[3]};
    v4f vov = {vo[0], vo[1], vo[2], vo[3]};
    *reinterpret_cast<v4f*>(&probs_out[base + j0]) = pov;
    *reinterpret_cast<v4f*>(&vels_out[base + j0]) = vov;
}

// ---------- launch ----------

extern "C" void kernel_launch(void* const* d_in, const int* in_sizes, int n_in,
                              void* d_out, int out_size, void* d_ws, size_t ws_size,
                              hipStream_t stream) {
    const float* onset = (const float*)d_in[0];
    const float* vel   = (const float*)d_in[1];
    const float* pth   = (const float*)d_in[2];

    const int n = in_sizes[0];            // B*K*T = 23068672
    const int rows = n / T_DIM;           // 704
    float* probs_out = (float*)d_out;
    float* vels_out  = probs_out + (size_t)n;
    uint32_t* wsu = (uint32_t*)d_ws;

    // Gaussian weights in f32 semantics matching the reference.
    float e[7];
    for (int i = 0; i < 7; ++i) {
        float xi = (float)i - 3.0f;
        float arg = -0.5f * (xi * xi);
        e[i] = (float)exp((double)arg);
    }
    float s = e[0];
    for (int i = 1; i < 7; ++i) s += e[i];
    float w[7];
    for (int i = 0; i < 7; ++i) w[i] = e[i] / s;

    dim3 grid(T_DIM / (4 * BLOCK), rows);   // (32, 704)

    init_ws_kernel<<<1, 1, 0, stream>>>(wsu);
    fused_kernel<<<grid, BLOCK, 0, stream>>>(
        onset, vel, pth, wsu, probs_out, vels_out,
        w[0], w[1], w[2], w[3], w[4], w[5], w[6]);
    fixup_kernel<<<grid, BLOCK, 0, stream>>>(
        onset, vel, pth, wsu, probs_out, vels_out);
}